// Round 2
// baseline (245.442 us; speedup 1.0000x reference)
//
#include <hip/hip_runtime.h>

typedef float  f32x4  __attribute__((ext_vector_type(4)));
typedef float  f32x2  __attribute__((ext_vector_type(2)));
typedef short  bf16x8 __attribute__((ext_vector_type(8)));

#define TWOLOG2E   2.8853900817779268f
#define NLOG2E    -1.4426950408889634f
#define NTWOLOG2E -2.8853900817779268f

__device__ __forceinline__ unsigned short f2b(float f) {      // fp32 -> bf16 RNE
    unsigned int u = __builtin_bit_cast(unsigned int, f);
    u += 0x7fffu + ((u >> 16) & 1u);
    return (unsigned short)(u >> 16);
}
__device__ __forceinline__ float b2f(unsigned short s) {
    unsigned int u = ((unsigned int)s) << 16;
    return __builtin_bit_cast(float, u);
}
__device__ __forceinline__ unsigned int pk2(float lo, float hi) {
#if __has_builtin(__builtin_amdgcn_cvt_pk_bf16_f32)
    typedef __bf16 bf16x2 __attribute__((ext_vector_type(2)));
    bf16x2 p = __builtin_amdgcn_cvt_pk_bf16_f32(lo, hi);
    return __builtin_bit_cast(unsigned int, p);
#else
    return (unsigned int)f2b(lo) | ((unsigned int)f2b(hi) << 16);
#endif
}
__device__ __forceinline__ float frcp(float x) { return __builtin_amdgcn_rcpf(x); }
__device__ __forceinline__ float fex2(float x) { return __builtin_amdgcn_exp2f(x); }

// R15: occupancy bet. Counters said latency-starved (VALU 58 + MFMA 17 + 25%
// idle at 2 waves/SIMD, grid-limited). This version: 16 rows/block, grid 1024
// (= exactly 4 blocks/CU), register diet to fit 4 waves/SIMD in the 512-reg
// per-SIMD pool: cbq bias-quads dropped (MFMA C = zero; bias via v_pk_add in
// epilogue, bvp pairs 8 regs), single row-tile per wave (a0/a1 scalar, cp2[4]).
// __launch_bounds__(256,4) forces <=128 regs/wave. LDS 24.6KB/block -> 98KB/CU.
// Pipeline structure unchanged from R9/R14: wave l owns layer l, 2-timestep
// super-steps, 35 barriers, B-frags pre-scaled by -log2e (-2log2e for g),
// packed-FP32 epilogue (R14), 5 exp2 + 2 rcp per unit (exact-math floor):
//   p1=(1+ei)(1+eg); cn' = [cp*p1 - 2log2e(1-eg)(1+ef)] * rcp(p1*(1+ef))
//   (cp = -2log2e*c);  ec = exp2(cp);  h = (1-ec)*rcp((1+eo)(1+ec))
__global__ __launch_bounds__(256, 4)
void lstm_mfma(const float* __restrict__ xg,  const float* __restrict__ Wih0,
               const float* __restrict__ Wih, const float* __restrict__ Whh,
               const float* __restrict__ bih, const float* __restrict__ bhh,
               const float* __restrict__ Wlin,const float* __restrict__ blin,
               float* __restrict__ out) {
    __shared__ short        hb[16 * 640] __attribute__((aligned(16))); // [l][p][slot][16row*40]
    __shared__ unsigned int xb[64 * 16];                               // [t][row] 2xbf16

    const int tid  = threadIdx.x;
    const int wv   = __builtin_amdgcn_readfirstlane(tid >> 6);  // layer id, uniform
    const int lane = tid & 63;
    const int m    = lane & 15;    // A-row / D-col index
    const int q    = lane >> 4;    // quad
    const int row0 = blockIdx.x * 16;

    // zero all h buffers (first reads must see 0)
    for (int i = tid; i < 5120; i += 256) ((unsigned int*)hb)[i] = 0u;

    // stage x -> LDS bf16 [t][row]
    for (int i = tid; i < 1024; i += 256) {
        int r = i >> 6, t = i & 63;
        float x0 = xg[(size_t)(row0 + r) * 192 + t];
        float x1 = xg[(size_t)(row0 + r) * 192 + 64 + t];
        xb[t * 16 + r] = pk2(x0, x1);
    }

    // ---- one-time gather of B-frags + bias (negated scales) ----
    // tile g: gate T=g>>1 of unit 2m+(g&1); rowG = T*32 + 2m + (g&1).
    bf16x8 bfr[8][2];
    float  bv[8];
#pragma unroll
    for (int g = 0; g < 8; ++g) {
        const int   T    = g >> 1;
        const int   rowG = T * 32 + 2 * m + (g & 1);
        const float sc   = (T == 2) ? NTWOLOG2E : NLOG2E;
        bv[g] = (bih[wv * 128 + rowG] + bhh[wv * 128 + rowG]) * sc;
#pragma unroll
        for (int c = 0; c < 2; ++c) {
            const int k0 = c * 32 + q * 8;
            float w[8];
            if (wv == 0) {
                if (c == 0) {
#pragma unroll
                    for (int jj = 0; jj < 8; ++jj) w[jj] = 0.0f;
                    if (q == 0) { w[0] = Wih0[rowG * 2]; w[1] = Wih0[rowG * 2 + 1]; }
                } else {
                    const float* src = Whh + rowG * 32 + (k0 - 32);
#pragma unroll
                    for (int jj = 0; jj < 8; ++jj) w[jj] = src[jj];
                }
            } else {
                const float* src = (c == 0) ? (Wih + (wv - 1) * 4096 + rowG * 32 + k0)
                                            : (Whh + wv * 4096 + rowG * 32 + (k0 - 32));
#pragma unroll
                for (int jj = 0; jj < 8; ++jj) w[jj] = src[jj];
            }
            bf16x8 fr;
#pragma unroll
            for (int jj = 0; jj < 8; ++jj) fr[jj] = (short)f2b(w[jj] * sc);
            bfr[g][c] = fr;
        }
    }

    // bias as packed pairs (tile 2T pairs with 2T+1), replaces 32-reg cbq
    f32x2 bvp[4];
#pragma unroll
    for (int T = 0; T < 4; ++T) bvp[T] = (f32x2){bv[2 * T], bv[2 * T + 1]};

    f32x2 cp2[4];   // scaled cell state -2log2e*c: [r], .x=hf0 .y=hf1
#pragma unroll
    for (int r = 0; r < 4; ++r) cp2[r] = (f32x2){0.0f, 0.0f};

    // hoisted per-lane LDS offsets
    const int aoff = m * 40 + q * 8;        // short-index A-frag offset within slot
    const int woff = q * 80 + m;            // uint-index h-write offset within slot

    __syncthreads();

    // one t cell-step for all 16 rows (single row-tile)
    auto cell_step = [&](int t, const short* pa0, const short* pa1, short* hwr) {
        bf16x8 a0, a1;
        if (wv == 0) {
            unsigned int xd = xb[t * 16 + m];
            union { unsigned int u[4]; bf16x8 v; } au;
            au.u[0] = (q == 0) ? xd : 0u; au.u[1] = 0u; au.u[2] = 0u; au.u[3] = 0u;
            a0 = au.v;
        } else {
            a0 = *(const bf16x8*)(pa0 + aoff);
        }
        a1 = *(const bf16x8*)(pa1 + aoff);

        const f32x4 zq = {0.0f, 0.0f, 0.0f, 0.0f};
        f32x4 acc[8];
#pragma unroll
        for (int g = 0; g < 8; ++g) {
            acc[g] = __builtin_amdgcn_mfma_f32_16x16x32_bf16(a0, bfr[g][0], zq, 0, 0, 0);
            acc[g] = __builtin_amdgcn_mfma_f32_16x16x32_bf16(a1, bfr[g][1], acc[g], 0, 0, 0);
        }
        const f32x2 one  = {1.0f, 1.0f};
        const f32x2 c2l  = {TWOLOG2E, TWOLOG2E};
        const f32x2 n2l  = {NTWOLOG2E, NTWOLOG2E};
#pragma unroll
        for (int r = 0; r < 4; ++r) {
            f32x2 gi = (f32x2){acc[0][r], acc[1][r]} + bvp[0];
            f32x2 gf = (f32x2){acc[2][r], acc[3][r]} + bvp[1];
            f32x2 gg = (f32x2){acc[4][r], acc[5][r]} + bvp[2];
            f32x2 go = (f32x2){acc[6][r], acc[7][r]} + bvp[3];
            f32x2 ei = {fex2(gi.x), fex2(gi.y)};              // e^{-a_i}, both hf halves
            f32x2 ef = {fex2(gf.x), fex2(gf.y)};              // e^{-a_f}
            f32x2 eg = {fex2(gg.x), fex2(gg.y)};              // e^{-2 a_g}
            f32x2 eo = {fex2(go.x), fex2(go.y)};              // e^{-a_o}
            f32x2 apf = one + ef;
            f32x2 p1  = (one + ei) * (one + eg);
            f32x2 Dc  = p1 * apf;
            f32x2 R_  = {frcp(Dc.x), frcp(Dc.y)};
            f32x2 egp = __builtin_elementwise_fma(eg, c2l, n2l);  // -2log2e*(1-eg)
            f32x2 t1  = egp * apf;
            f32x2 t2  = __builtin_elementwise_fma(cp2[r], p1, t1);
            f32x2 cn  = t2 * R_;                              // scaled cell state
            cp2[r] = cn;
            f32x2 ec  = {fex2(cn.x), fex2(cn.y)};             // e^{-2c}
            f32x2 Dh  = (one + eo) * (one + ec);
            f32x2 Rh  = {frcp(Dh.x), frcp(Dh.y)};
            f32x2 hh  = (one - ec) * Rh;
            ((unsigned int*)hwr)[woff + r * 20] = pk2(hh.x, hh.y);
        }
    };

    for (int S = 0; S < 35; ++S) {
        const int t0 = 2 * (S - wv);          // wave-uniform
        if (t0 >= 0 && t0 <= 62) {
            const int p  = S & 1;
            const int pb = p ^ 1;
            short*       Lc0 = hb + ((wv * 2 + p ) * 2    ) * 640;   // own layer, cur parity, slot0
            short*       Lc1 = Lc0 + 640;                             // slot1
            const short* Lp1 = hb + ((wv * 2 + pb) * 2 + 1) * 640;   // own layer, prev parity, slot1
            const int    lb  = (wv > 0) ? (wv - 1) : 0;
            const short* Dp0 = hb + ((lb * 2 + pb) * 2    ) * 640;   // layer below, prev parity, slot0
            const short* Dp1 = Dp0 + 640;                             // slot1

            cell_step(t0,     Dp0, Lp1, Lc0);   // t0: input h_{l-1}(t0), recurrent h_l(t0-1)
            cell_step(t0 + 1, Dp1, Lc0, Lc1);   // t1: input h_{l-1}(t1), recurrent h_l(t0)
        }
        __syncthreads();
    }

    // output head: h3(t=63) -> S=34, p=0, slot1
    if (tid < 16) {
        const short* h3 = hb + ((3 * 2 + 0) * 2 + 1) * 640;
        float s = blin[0];
#pragma unroll
        for (int k = 0; k < 32; ++k)
            s += Wlin[k] * b2f((unsigned short)h3[tid * 40 + k]);
        out[row0 + tid] = frcp(1.0f + fex2(s * NLOG2E));
    }
}

extern "C" void kernel_launch(void* const* d_in, const int* in_sizes, int n_in,
                              void* d_out, int out_size, void* d_ws, size_t ws_size,
                              hipStream_t stream) {
    const float* x    = (const float*)d_in[0];
    const float* Wih0 = (const float*)d_in[1];
    const float* Wih  = (const float*)d_in[2];
    const float* Whh  = (const float*)d_in[3];
    const float* bih  = (const float*)d_in[4];
    const float* bhh  = (const float*)d_in[5];
    const float* Wlin = (const float*)d_in[6];
    const float* blin = (const float*)d_in[7];
    float* out = (float*)d_out;

    lstm_mfma<<<1024, 256, 0, stream>>>(x, Wih0, Wih, Whh, bih, bhh, Wlin, blin, out);
}

// Round 3
// 231.577 us; speedup vs baseline: 1.0599x; 1.0599x over previous
//
#include <hip/hip_runtime.h>

typedef float  f32x4  __attribute__((ext_vector_type(4)));
typedef float  f32x2  __attribute__((ext_vector_type(2)));
typedef short  bf16x8 __attribute__((ext_vector_type(8)));

#define TWOLOG2E   2.8853900817779268f
#define NLOG2E    -1.4426950408889634f
#define NTWOLOG2E -2.8853900817779268f

__device__ __forceinline__ unsigned short f2b(float f) {      // fp32 -> bf16 RNE
    unsigned int u = __builtin_bit_cast(unsigned int, f);
    u += 0x7fffu + ((u >> 16) & 1u);
    return (unsigned short)(u >> 16);
}
__device__ __forceinline__ float b2f(unsigned short s) {
    unsigned int u = ((unsigned int)s) << 16;
    return __builtin_bit_cast(float, u);
}
__device__ __forceinline__ unsigned int pk2(float lo, float hi) {
#if __has_builtin(__builtin_amdgcn_cvt_pk_bf16_f32)
    typedef __bf16 bf16x2 __attribute__((ext_vector_type(2)));
    bf16x2 p = __builtin_amdgcn_cvt_pk_bf16_f32(lo, hi);
    return __builtin_bit_cast(unsigned int, p);
#else
    return (unsigned int)f2b(lo) | ((unsigned int)f2b(hi) << 16);
#endif
}
__device__ __forceinline__ float frcp(float x) { return __builtin_amdgcn_rcpf(x); }
__device__ __forceinline__ float fex2(float x) { return __builtin_amdgcn_exp2f(x); }

// R16: cross-timestep MFMA overlap. R14 shape (32 rows/block, grid 512, 2
// blocks/CU = 2 waves/SIMD, wave l owns layer l, 35 barriers) — R15 proved
// 4 waves/SIMD can't hold the weight-stationary set (spill storm: WRITE_SIZE
// 64KB->49MB). Occupancy is structurally capped; attack the in-superstep
// serial chain instead. t1's down-input (layer below, Dp1) is independent of
// t0's epilogue: hoist its loads + 16 down-MFMAs between t0's two tile
// epilogues so they fill the trans-pipe latency gaps. Only t1's recurrent
// half (read-after-write of Lc0) stays serial. Bias moved from 32-reg cbq
// C-operand to 8-reg packed epilogue adds (bvp) to keep peak regs ~220 < 256.
// Epilogue math unchanged (5 exp2 + 2 rcp / unit, packed f32x2 pairs):
//   p1=(1+ei)(1+eg); cn' = [cp*p1 - 2log2e(1-eg)(1+ef)] * rcp(p1*(1+ef))
//   (cp = -2log2e*c);  ec = exp2(cp);  h = (1-ec)*rcp((1+eo)(1+ec))
__global__ __launch_bounds__(256, 2)
void lstm_mfma(const float* __restrict__ xg,  const float* __restrict__ Wih0,
               const float* __restrict__ Wih, const float* __restrict__ Whh,
               const float* __restrict__ bih, const float* __restrict__ bhh,
               const float* __restrict__ Wlin,const float* __restrict__ blin,
               float* __restrict__ out) {
    __shared__ short        hb[16 * 1280] __attribute__((aligned(16))); // [l][p][slot][32row*40]
    __shared__ unsigned int xb[64 * 32];                                // [t][row] 2xbf16

    const int tid  = threadIdx.x;
    const int wv   = __builtin_amdgcn_readfirstlane(tid >> 6);  // layer id, uniform
    const int lane = tid & 63;
    const int m    = lane & 15;    // A-row / D-col index
    const int q    = lane >> 4;    // quad
    const int row0 = blockIdx.x * 32;

    // zero all h buffers (first reads must see 0)
    for (int i = tid; i < 10240; i += 256) ((unsigned int*)hb)[i] = 0u;

    // stage x -> LDS bf16 [t][row]
    for (int i = tid; i < 2048; i += 256) {
        int r = i >> 6, t = i & 63;
        float x0 = xg[(size_t)(row0 + r) * 192 + t];
        float x1 = xg[(size_t)(row0 + r) * 192 + 64 + t];
        xb[t * 32 + r] = pk2(x0, x1);
    }

    // ---- one-time gather of B-frags + bias (negated scales) ----
    // tile g: gate T=g>>1 of unit 2m+(g&1); rowG = T*32 + 2m + (g&1).
    bf16x8 bfr[8][2];
    float  bv[8];
#pragma unroll
    for (int g = 0; g < 8; ++g) {
        const int   T    = g >> 1;
        const int   rowG = T * 32 + 2 * m + (g & 1);
        const float sc   = (T == 2) ? NTWOLOG2E : NLOG2E;
        bv[g] = (bih[wv * 128 + rowG] + bhh[wv * 128 + rowG]) * sc;
#pragma unroll
        for (int c = 0; c < 2; ++c) {
            const int k0 = c * 32 + q * 8;
            float w[8];
            if (wv == 0) {
                if (c == 0) {
#pragma unroll
                    for (int jj = 0; jj < 8; ++jj) w[jj] = 0.0f;
                    if (q == 0) { w[0] = Wih0[rowG * 2]; w[1] = Wih0[rowG * 2 + 1]; }
                } else {
                    const float* src = Whh + rowG * 32 + (k0 - 32);
#pragma unroll
                    for (int jj = 0; jj < 8; ++jj) w[jj] = src[jj];
                }
            } else {
                const float* src = (c == 0) ? (Wih + (wv - 1) * 4096 + rowG * 32 + k0)
                                            : (Whh + wv * 4096 + rowG * 32 + (k0 - 32));
#pragma unroll
                for (int jj = 0; jj < 8; ++jj) w[jj] = src[jj];
            }
            bf16x8 fr;
#pragma unroll
            for (int jj = 0; jj < 8; ++jj) fr[jj] = (short)f2b(w[jj] * sc);
            bfr[g][c] = fr;
        }
    }

    // bias as packed pairs (tile 2T pairs with 2T+1) applied in epilogue
    f32x2 bvp[4];
#pragma unroll
    for (int T = 0; T < 4; ++T) bvp[T] = (f32x2){bv[2 * T], bv[2 * T + 1]};

    f32x2 cp2[2][4];   // scaled cell state -2log2e*c: [tile][r], .x=hf0 .y=hf1
#pragma unroll
    for (int tt = 0; tt < 2; ++tt)
#pragma unroll
        for (int r = 0; r < 4; ++r) cp2[tt][r] = (f32x2){0.0f, 0.0f};

    // hoisted per-lane LDS offsets
    const int aoff = m * 40 + q * 8;        // short-index A-frag offset within slot
    const int woff = q * 80 + m;            // uint-index h-write offset within slot

    __syncthreads();

    // load both 16-row tiles of a down-input (x for wave 0, else LDS A-frags)
    auto load_down = [&](int t, const short* pa, bf16x8* dst) {
        if (wv == 0) {
#pragma unroll
            for (int tt = 0; tt < 2; ++tt) {
                unsigned int xd = xb[t * 32 + tt * 16 + m];
                union { unsigned int u[4]; bf16x8 v; } au;
                au.u[0] = (q == 0) ? xd : 0u; au.u[1] = 0u; au.u[2] = 0u; au.u[3] = 0u;
                dst[tt] = au.v;
            }
        } else {
#pragma unroll
            for (int tt = 0; tt < 2; ++tt)
                dst[tt] = *(const bf16x8*)(pa + aoff + tt * 640);
        }
    };
    auto load_rec = [&](const short* pa, bf16x8* dst) {
#pragma unroll
        for (int tt = 0; tt < 2; ++tt)
            dst[tt] = *(const bf16x8*)(pa + aoff + tt * 640);
    };

    // epilogue for one 16-row tile (8 gate accs), writes h bf16 pairs to LDS
    auto epi_tile = [&](const f32x4* a8, f32x2* cpr, short* hwr, int tt) {
        const f32x2 one = {1.0f, 1.0f};
        const f32x2 c2l = {TWOLOG2E, TWOLOG2E};
        const f32x2 n2l = {NTWOLOG2E, NTWOLOG2E};
#pragma unroll
        for (int r = 0; r < 4; ++r) {
            f32x2 gi = (f32x2){a8[0][r], a8[1][r]} + bvp[0];
            f32x2 gf = (f32x2){a8[2][r], a8[3][r]} + bvp[1];
            f32x2 gg = (f32x2){a8[4][r], a8[5][r]} + bvp[2];
            f32x2 go = (f32x2){a8[6][r], a8[7][r]} + bvp[3];
            f32x2 ei = {fex2(gi.x), fex2(gi.y)};              // e^{-a_i}
            f32x2 ef = {fex2(gf.x), fex2(gf.y)};              // e^{-a_f}
            f32x2 eg = {fex2(gg.x), fex2(gg.y)};              // e^{-2 a_g}
            f32x2 eo = {fex2(go.x), fex2(go.y)};              // e^{-a_o}
            f32x2 apf = one + ef;
            f32x2 p1  = (one + ei) * (one + eg);
            f32x2 Dc  = p1 * apf;
            f32x2 R_  = {frcp(Dc.x), frcp(Dc.y)};
            f32x2 egp = __builtin_elementwise_fma(eg, c2l, n2l);  // -2log2e*(1-eg)
            f32x2 t1  = egp * apf;
            f32x2 t2  = __builtin_elementwise_fma(cpr[r], p1, t1);
            f32x2 cn  = t2 * R_;                              // scaled cell state
            cpr[r] = cn;
            f32x2 ec  = {fex2(cn.x), fex2(cn.y)};             // e^{-2c}
            f32x2 Dh  = (one + eo) * (one + ec);
            f32x2 Rh  = {frcp(Dh.x), frcp(Dh.y)};
            f32x2 hh  = (one - ec) * Rh;
            ((unsigned int*)hwr)[woff + tt * 320 + r * 20] = pk2(hh.x, hh.y);
        }
    };

    const f32x4 zq = {0.0f, 0.0f, 0.0f, 0.0f};

    for (int S = 0; S < 35; ++S) {
        const int t0 = 2 * (S - wv);          // wave-uniform
        if (t0 >= 0 && t0 <= 62) {
            const int p  = S & 1;
            const int pb = p ^ 1;
            short*       Lc0 = hb + ((wv * 2 + p ) * 2    ) * 1280;  // own layer, cur parity, slot0
            short*       Lc1 = Lc0 + 1280;                            // slot1
            const short* Lp1 = hb + ((wv * 2 + pb) * 2 + 1) * 1280;  // own layer, prev parity, slot1
            const int    lb  = (wv > 0) ? (wv - 1) : 0;
            const short* Dp0 = hb + ((lb * 2 + pb) * 2    ) * 1280;  // layer below, prev parity, slot0
            const short* Dp1 = Dp0 + 1280;                            // slot1

            // ---- all barrier-independent loads up front ----
            bf16x8 a0d[2], a0r[2], a1d[2];
            load_down(t0,     Dp0, a0d);   // t0 input h_{l-1}(t0)
            load_rec (Lp1,         a0r);   // t0 recurrent h_l(t0-1)
            load_down(t0 + 1, Dp1, a1d);   // t1 input h_{l-1}(t1)  [independent of t0!]

            // ---- t0 full MFMA ----
            f32x4 acc0[2][8], acc1[2][8];
#pragma unroll
            for (int tt = 0; tt < 2; ++tt)
#pragma unroll
                for (int g = 0; g < 8; ++g) {
                    acc0[tt][g] = __builtin_amdgcn_mfma_f32_16x16x32_bf16(a0d[tt], bfr[g][0], zq, 0, 0, 0);
                    acc0[tt][g] = __builtin_amdgcn_mfma_f32_16x16x32_bf16(a0r[tt], bfr[g][1], acc0[tt][g], 0, 0, 0);
                }

            // ---- epilogue t0 tile0; t1 down-MFMAs interleave with its trans latency ----
            epi_tile(acc0[0], cp2[0], Lc0, 0);
#pragma unroll
            for (int tt = 0; tt < 2; ++tt)
#pragma unroll
                for (int g = 0; g < 8; ++g)
                    acc1[tt][g] = __builtin_amdgcn_mfma_f32_16x16x32_bf16(a1d[tt], bfr[g][0], zq, 0, 0, 0);
            epi_tile(acc0[1], cp2[1], Lc0, 1);

            // ---- t1 recurrent half (true RAW on Lc0) ----
            bf16x8 a1r[2];
            load_rec(Lc0, a1r);
#pragma unroll
            for (int tt = 0; tt < 2; ++tt)
#pragma unroll
                for (int g = 0; g < 8; ++g)
                    acc1[tt][g] = __builtin_amdgcn_mfma_f32_16x16x32_bf16(a1r[tt], bfr[g][1], acc1[tt][g], 0, 0, 0);
            epi_tile(acc1[0], cp2[0], Lc1, 0);
            epi_tile(acc1[1], cp2[1], Lc1, 1);
        }
        __syncthreads();
    }

    // output head: h3(t=63) -> S=34, p=0, slot1
    if (tid < 32) {
        const short* h3 = hb + ((3 * 2 + 0) * 2 + 1) * 1280;
        float s = blin[0];
#pragma unroll
        for (int k = 0; k < 32; ++k)
            s += Wlin[k] * b2f((unsigned short)h3[tid * 40 + k]);
        out[row0 + tid] = frcp(1.0f + fex2(s * NLOG2E));
    }
}

extern "C" void kernel_launch(void* const* d_in, const int* in_sizes, int n_in,
                              void* d_out, int out_size, void* d_ws, size_t ws_size,
                              hipStream_t stream) {
    const float* x    = (const float*)d_in[0];
    const float* Wih0 = (const float*)d_in[1];
    const float* Wih  = (const float*)d_in[2];
    const float* Whh  = (const float*)d_in[3];
    const float* bih  = (const float*)d_in[4];
    const float* bhh  = (const float*)d_in[5];
    const float* Wlin = (const float*)d_in[6];
    const float* blin = (const float*)d_in[7];
    float* out = (float*)d_out;

    lstm_mfma<<<512, 256, 0, stream>>>(x, Wih0, Wih, Whh, bih, bhh, Wlin, blin, out);
}

// Round 4
// 217.373 us; speedup vs baseline: 1.1291x; 1.0653x over previous
//
#include <hip/hip_runtime.h>

typedef float  f32x4  __attribute__((ext_vector_type(4)));
typedef float  f32x2  __attribute__((ext_vector_type(2)));
typedef short  bf16x8 __attribute__((ext_vector_type(8)));

#define TWOLOG2E   2.8853900817779268f
#define NLOG2E    -1.4426950408889634f
#define NTWOLOG2E -2.8853900817779268f

__device__ __forceinline__ unsigned short f2b(float f) {      // fp32 -> bf16 RNE
    unsigned int u = __builtin_bit_cast(unsigned int, f);
    u += 0x7fffu + ((u >> 16) & 1u);
    return (unsigned short)(u >> 16);
}
__device__ __forceinline__ float b2f(unsigned short s) {
    unsigned int u = ((unsigned int)s) << 16;
    return __builtin_bit_cast(float, u);
}
__device__ __forceinline__ unsigned int pk2(float lo, float hi) {
#if __has_builtin(__builtin_amdgcn_cvt_pk_bf16_f32)
    typedef __bf16 bf16x2 __attribute__((ext_vector_type(2)));
    bf16x2 p = __builtin_amdgcn_cvt_pk_bf16_f32(lo, hi);
    return __builtin_bit_cast(unsigned int, p);
#else
    return (unsigned int)f2b(lo) | ((unsigned int)f2b(hi) << 16);
#endif
}
__device__ __forceinline__ float frcp(float x) { return __builtin_amdgcn_rcpf(x); }
__device__ __forceinline__ float fex2(float x) { return __builtin_amdgcn_exp2f(x); }

// R17: R14 structure (best known: 32 rows/block, grid 512, 2 blocks/CU = 2
// waves/SIMD, wave l owns layer l, 2-timestep supersteps, 35 barriers, bias in
// MFMA C operand cbq, B-frags pre-scaled by -log2e / -2log2e) with the packed
// epilogue re-paired along the ROW axis: f32x2 operands are acc[g].xy/.zw
// sub-register pairs of the MFMA dst quad (zero v_mov formation), instead of
// {acc[even][r],acc[odd][r]} cross-quad pairs (2 movs each, ~128 movs/superstep).
// Two packed chains per row-pair (unit 2m and 2m+1); pk2 re-pairs units at the
// end (same cvt + LDS-write count). Per-element math identical -> bit-exact.
// Epilogue math (5 exp2 + 2 rcp / unit, exact-math floor):
//   p1=(1+ei)(1+eg); cn' = [cp*p1 - 2log2e(1-eg)(1+ef)] * rcp(p1*(1+ef))
//   (cp = -2log2e*c);  ec = exp2(cp);  h = (1-ec)*rcp((1+eo)(1+ec))
// History: R15 4-waves/SIMD -> spill storm (occupancy structurally capped at 2);
// R16 manual cross-timestep overlap -> +20us VALU (AGPR moves); reverted.
__global__ __launch_bounds__(256, 2)
void lstm_mfma(const float* __restrict__ xg,  const float* __restrict__ Wih0,
               const float* __restrict__ Wih, const float* __restrict__ Whh,
               const float* __restrict__ bih, const float* __restrict__ bhh,
               const float* __restrict__ Wlin,const float* __restrict__ blin,
               float* __restrict__ out) {
    __shared__ short        hb[16 * 1280] __attribute__((aligned(16))); // [l][p][slot][32row*40]
    __shared__ unsigned int xb[64 * 32];                                // [t][row] 2xbf16

    const int tid  = threadIdx.x;
    const int wv   = __builtin_amdgcn_readfirstlane(tid >> 6);  // layer id, uniform
    const int lane = tid & 63;
    const int m    = lane & 15;    // A-row / D-col index
    const int q    = lane >> 4;    // quad
    const int row0 = blockIdx.x * 32;

    // zero all h buffers (first reads must see 0)
    for (int i = tid; i < 10240; i += 256) ((unsigned int*)hb)[i] = 0u;

    // stage x -> LDS bf16 [t][row]
    for (int i = tid; i < 2048; i += 256) {
        int r = i >> 6, t = i & 63;
        float x0 = xg[(size_t)(row0 + r) * 192 + t];
        float x1 = xg[(size_t)(row0 + r) * 192 + 64 + t];
        xb[t * 32 + r] = pk2(x0, x1);
    }

    // ---- one-time gather of B-frags + bias (negated scales) ----
    // tile g: gate T=g>>1 of unit 2m+(g&1); rowG = T*32 + 2m + (g&1).
    bf16x8 bfr[8][2];
    float  bv[8];
#pragma unroll
    for (int g = 0; g < 8; ++g) {
        const int   T    = g >> 1;
        const int   rowG = T * 32 + 2 * m + (g & 1);
        const float sc   = (T == 2) ? NTWOLOG2E : NLOG2E;
        bv[g] = (bih[wv * 128 + rowG] + bhh[wv * 128 + rowG]) * sc;
#pragma unroll
        for (int c = 0; c < 2; ++c) {
            const int k0 = c * 32 + q * 8;
            float w[8];
            if (wv == 0) {
                if (c == 0) {
#pragma unroll
                    for (int jj = 0; jj < 8; ++jj) w[jj] = 0.0f;
                    if (q == 0) { w[0] = Wih0[rowG * 2]; w[1] = Wih0[rowG * 2 + 1]; }
                } else {
                    const float* src = Whh + rowG * 32 + (k0 - 32);
#pragma unroll
                    for (int jj = 0; jj < 8; ++jj) w[jj] = src[jj];
                }
            } else {
                const float* src = (c == 0) ? (Wih + (wv - 1) * 4096 + rowG * 32 + k0)
                                            : (Whh + wv * 4096 + rowG * 32 + (k0 - 32));
#pragma unroll
                for (int jj = 0; jj < 8; ++jj) w[jj] = src[jj];
            }
            bf16x8 fr;
#pragma unroll
            for (int jj = 0; jj < 8; ++jj) fr[jj] = (short)f2b(w[jj] * sc);
            bfr[g][c] = fr;
        }
    }

    // hoisted bias C-operand quads (persistent; bias rides into MFMA)
    f32x4 cbq[8];
#pragma unroll
    for (int g = 0; g < 8; ++g) {
        f32x4 c4 = {bv[g], bv[g], bv[g], bv[g]};
        cbq[g] = c4;
    }

    // scaled cell state -2log2e*c: [tt][hf][rp], f32x2 over row-pair (2rp,2rp+1)
    f32x2 cp2[2][2][2];
#pragma unroll
    for (int tt = 0; tt < 2; ++tt)
#pragma unroll
        for (int hf = 0; hf < 2; ++hf)
#pragma unroll
            for (int rp = 0; rp < 2; ++rp) cp2[tt][hf][rp] = (f32x2){0.0f, 0.0f};

    // hoisted per-lane LDS offsets
    const int aoff = m * 40 + q * 8;        // short-index A-frag offset within slot
    const int woff = q * 80 + m;            // uint-index h-write offset within slot

    __syncthreads();

    // packed LSTM epilogue chain over a row-pair for one unit column
    auto chain = [&](f32x2 ai, f32x2 af, f32x2 ag, f32x2 ao, f32x2& cpr) -> f32x2 {
        const f32x2 one = {1.0f, 1.0f};
        const f32x2 c2l = {TWOLOG2E, TWOLOG2E};
        const f32x2 n2l = {NTWOLOG2E, NTWOLOG2E};
        f32x2 ei = {fex2(ai.x), fex2(ai.y)};              // e^{-a_i}
        f32x2 ef = {fex2(af.x), fex2(af.y)};              // e^{-a_f}
        f32x2 eg = {fex2(ag.x), fex2(ag.y)};              // e^{-2 a_g}
        f32x2 eo = {fex2(ao.x), fex2(ao.y)};              // e^{-a_o}
        f32x2 apf = one + ef;
        f32x2 p1  = (one + ei) * (one + eg);
        f32x2 Dc  = p1 * apf;
        f32x2 R_  = {frcp(Dc.x), frcp(Dc.y)};
        f32x2 egp = __builtin_elementwise_fma(eg, c2l, n2l);  // -2log2e*(1-eg)
        f32x2 t1  = egp * apf;
        f32x2 t2  = __builtin_elementwise_fma(cpr, p1, t1);
        f32x2 cn  = t2 * R_;                              // scaled cell state
        cpr = cn;
        f32x2 ec  = {fex2(cn.x), fex2(cn.y)};             // e^{-2c}
        f32x2 Dh  = (one + eo) * (one + ec);
        f32x2 Rh  = {frcp(Dh.x), frcp(Dh.y)};
        return (one - ec) * Rh;
    };

    // one t cell-step for all 32 rows (2 row-tiles)
    auto cell_step = [&](int t, const short* pa0, const short* pa1, short* hwr) {
        bf16x8 a0[2], a1[2];
#pragma unroll
        for (int tt = 0; tt < 2; ++tt) {
            if (wv == 0) {
                unsigned int xd = xb[t * 32 + tt * 16 + m];
                union { unsigned int u[4]; bf16x8 v; } au;
                au.u[0] = (q == 0) ? xd : 0u; au.u[1] = 0u; au.u[2] = 0u; au.u[3] = 0u;
                a0[tt] = au.v;
            } else {
                a0[tt] = *(const bf16x8*)(pa0 + aoff + tt * 640);
            }
            a1[tt] = *(const bf16x8*)(pa1 + aoff + tt * 640);
        }
#pragma unroll
        for (int tt = 0; tt < 2; ++tt) {
            f32x4 acc[8];
#pragma unroll
            for (int g = 0; g < 8; ++g) {
                acc[g] = __builtin_amdgcn_mfma_f32_16x16x32_bf16(a0[tt], bfr[g][0], cbq[g], 0, 0, 0);
                acc[g] = __builtin_amdgcn_mfma_f32_16x16x32_bf16(a1[tt], bfr[g][1], acc[g], 0, 0, 0);
            }
#pragma unroll
            for (int rp = 0; rp < 2; ++rp) {
                // sub-register f32x2 slices of the MFMA dst quads (no movs)
                f32x2 ai0 = rp ? (f32x2)__builtin_shufflevector(acc[0], acc[0], 2, 3)
                               : (f32x2)__builtin_shufflevector(acc[0], acc[0], 0, 1);
                f32x2 ai1 = rp ? (f32x2)__builtin_shufflevector(acc[1], acc[1], 2, 3)
                               : (f32x2)__builtin_shufflevector(acc[1], acc[1], 0, 1);
                f32x2 af0 = rp ? (f32x2)__builtin_shufflevector(acc[2], acc[2], 2, 3)
                               : (f32x2)__builtin_shufflevector(acc[2], acc[2], 0, 1);
                f32x2 af1 = rp ? (f32x2)__builtin_shufflevector(acc[3], acc[3], 2, 3)
                               : (f32x2)__builtin_shufflevector(acc[3], acc[3], 0, 1);
                f32x2 ag0 = rp ? (f32x2)__builtin_shufflevector(acc[4], acc[4], 2, 3)
                               : (f32x2)__builtin_shufflevector(acc[4], acc[4], 0, 1);
                f32x2 ag1 = rp ? (f32x2)__builtin_shufflevector(acc[5], acc[5], 2, 3)
                               : (f32x2)__builtin_shufflevector(acc[5], acc[5], 0, 1);
                f32x2 ao0 = rp ? (f32x2)__builtin_shufflevector(acc[6], acc[6], 2, 3)
                               : (f32x2)__builtin_shufflevector(acc[6], acc[6], 0, 1);
                f32x2 ao1 = rp ? (f32x2)__builtin_shufflevector(acc[7], acc[7], 2, 3)
                               : (f32x2)__builtin_shufflevector(acc[7], acc[7], 0, 1);

                f32x2 hh0 = chain(ai0, af0, ag0, ao0, cp2[tt][0][rp]);   // unit 2m
                f32x2 hh1 = chain(ai1, af1, ag1, ao1, cp2[tt][1][rp]);   // unit 2m+1

                ((unsigned int*)hwr)[woff + tt * 320 + (2 * rp    ) * 20] = pk2(hh0.x, hh1.x);
                ((unsigned int*)hwr)[woff + tt * 320 + (2 * rp + 1) * 20] = pk2(hh0.y, hh1.y);
            }
        }
    };

    for (int S = 0; S < 35; ++S) {
        const int t0 = 2 * (S - wv);          // wave-uniform
        if (t0 >= 0 && t0 <= 62) {
            const int p  = S & 1;
            const int pb = p ^ 1;
            short*       Lc0 = hb + ((wv * 2 + p ) * 2    ) * 1280;  // own layer, cur parity, slot0
            short*       Lc1 = Lc0 + 1280;                            // slot1
            const short* Lp1 = hb + ((wv * 2 + pb) * 2 + 1) * 1280;  // own layer, prev parity, slot1
            const int    lb  = (wv > 0) ? (wv - 1) : 0;
            const short* Dp0 = hb + ((lb * 2 + pb) * 2    ) * 1280;  // layer below, prev parity, slot0
            const short* Dp1 = Dp0 + 1280;                            // slot1

            cell_step(t0,     Dp0, Lp1, Lc0);   // t0: input h_{l-1}(t0), recurrent h_l(t0-1)
            cell_step(t0 + 1, Dp1, Lc0, Lc1);   // t1: input h_{l-1}(t1), recurrent h_l(t0)
        }
        __syncthreads();
    }

    // output head: h3(t=63) -> S=34, p=0, slot1
    if (tid < 32) {
        const short* h3 = hb + ((3 * 2 + 0) * 2 + 1) * 1280;
        float s = blin[0];
#pragma unroll
        for (int k = 0; k < 32; ++k)
            s += Wlin[k] * b2f((unsigned short)h3[tid * 40 + k]);
        out[row0 + tid] = frcp(1.0f + fex2(s * NLOG2E));
    }
}

extern "C" void kernel_launch(void* const* d_in, const int* in_sizes, int n_in,
                              void* d_out, int out_size, void* d_ws, size_t ws_size,
                              hipStream_t stream) {
    const float* x    = (const float*)d_in[0];
    const float* Wih0 = (const float*)d_in[1];
    const float* Wih  = (const float*)d_in[2];
    const float* Whh  = (const float*)d_in[3];
    const float* bih  = (const float*)d_in[4];
    const float* bhh  = (const float*)d_in[5];
    const float* Wlin = (const float*)d_in[6];
    const float* blin = (const float*)d_in[7];
    float* out = (float*)d_out;

    lstm_mfma<<<512, 256, 0, stream>>>(x, Wih0, Wih, Whh, bih, bhh, Wlin, blin, out);
}